// Round 3
// baseline (194.598 us; speedup 1.0000x reference)
//
#include <hip/hip_runtime.h>
#include <hip/hip_bf16.h>
#include <math.h>

// FreqActivation — harness compares only the REAL part of the complex64 ref
// (complex -> float32 cast drops imag; out_size = B*H*W*C = 16,777,216).
// real(out[b,h,w,c]) = relu(amp_raw)*cos(pi*tanh(ph_raw)) at source
//   (h,w)            if h+w <= 256   [top region + borders]
//   (256-h, 256-w)   if h+w >= 257   [mirrored bottom; conj doesn't affect real]
// Input [8,256,256,32,2] float32: 64 floats per (b,h,w), interleaved (amp,ph).
// Output [8,256,256,32] float32: 32 floats per (b,h,w).
// One thread = one output float4 (4 channels) = two input float4 loads.

#define PI_F 3.14159265358979323846f

__global__ __launch_bounds__(256) void freq_act_kernel(
    const float* __restrict__ in, float* __restrict__ out, int n_vec4)
{
    const int tid = blockIdx.x * 256 + threadIdx.x;
    if (tid >= n_vec4) return;

    const int c4 = tid & 7;           // which output float4 within the 32-float row
    const int w  = (tid >> 3)  & 255;
    const int h  = (tid >> 11) & 255;
    const int b  = tid >> 19;
    if (b >= 8) return;               // crash-proof if out_size semantics differ

    const bool top = (h + w) <= 256;
    const int  sh  = top ? h : 256 - h;
    const int  sw  = top ? w : 256 - w;

    // input row: 64 floats; this thread needs floats [c4*8, c4*8+8)
    const float* src = in + (((size_t)((b * 256 + sh) * 256 + sw)) << 6) + (c4 << 3);
    const float4 v0 = *reinterpret_cast<const float4*>(src);
    const float4 v1 = *reinterpret_cast<const float4*>(src + 4);

    float4 o;
    o.x = fmaxf(v0.x, 0.0f) * __cosf(PI_F * tanhf(v0.y));
    o.y = fmaxf(v0.z, 0.0f) * __cosf(PI_F * tanhf(v0.w));
    o.z = fmaxf(v1.x, 0.0f) * __cosf(PI_F * tanhf(v1.y));
    o.w = fmaxf(v1.z, 0.0f) * __cosf(PI_F * tanhf(v1.w));
    *reinterpret_cast<float4*>(out + ((size_t)tid << 2)) = o;
}

extern "C" void kernel_launch(void* const* d_in, const int* in_sizes, int n_in,
                              void* d_out, int out_size, void* d_ws, size_t ws_size,
                              hipStream_t stream)
{
    const float* in = (const float*)d_in[0];
    float* out = (float*)d_out;

    const int n_vec4 = out_size / 4;          // expected 4,194,304
    const int block = 256;
    const int grid = (n_vec4 + block - 1) / block;

    freq_act_kernel<<<grid, block, 0, stream>>>(in, out, n_vec4);
}